// Round 9
// baseline (145.129 us; speedup 1.0000x reference)
//
#include <hip/hip_runtime.h>

#define N_NODES 40000
#define N_EDGES 640000
#define D 128
#define ES_CAP 1280000   // padded edge capacity: 640000 + 40000*15 = 1.24M max

typedef __attribute__((ext_vector_type(8))) short short8;   // 8 bf16 = 4 VGPR
typedef __attribute__((ext_vector_type(4))) float f32x4;

__device__ __forceinline__ unsigned short f2bf(float f) {
    unsigned u = __float_as_uint(f);
    unsigned r = u + 0x7FFF + ((u >> 16) & 1);   // round-to-nearest-even
    return (unsigned short)(r >> 16);
}

#define BF_LO(u) __uint_as_float((u) << 16)
#define BF_HI(u) __uint_as_float((u) & 0xFFFF0000u)

// ---------------- fused prep: x->bf16, weight pack, degree count, ----------
// ---------------- edge_src sentinel fill, zero pad-rows, zero alloc ctr -----
// grid 2500 x 256 = 640000 threads. deg must be zeroed beforehand (memset).

__global__ __launch_bounds__(256) void prep_count(
    const float* __restrict__ x, unsigned short* __restrict__ xb,
    unsigned short* __restrict__ h1b,
    const float* __restrict__ Ws1, const float* __restrict__ Wn1,
    const float* __restrict__ Ws2, const float* __restrict__ Wn2,
    unsigned* __restrict__ Wp, const int* __restrict__ dst,
    int* __restrict__ deg, int* __restrict__ edge_src,
    int* __restrict__ alloc_ctr) {
    int t = blockIdx.x * 256 + threadIdx.x;

    if (t == 0) *alloc_ctr = 0;   // cursor for alloc_rows

    // sentinel-fill padded edge array (2 slots/thread covers ES_CAP)
    edge_src[t] = N_NODES;
    edge_src[t + 640000] = N_NODES;

    // zero the sentinel row of both feature planes (row N_NODES)
    if (t < 64) {
        ((unsigned*)xb)[N_NODES * 64 + t] = 0;
        ((unsigned*)h1b)[N_NODES * 64 + t] = 0;
    }

    // fp32 -> bf16 feature plane (8 elems/thread)
    {
        float4 a = ((const float4*)x)[t * 2];
        float4 b = ((const float4*)x)[t * 2 + 1];
        uint4 o;
        o.x = f2bf(a.x) | ((unsigned)f2bf(a.y) << 16);
        o.y = f2bf(a.z) | ((unsigned)f2bf(a.w) << 16);
        o.z = f2bf(b.x) | ((unsigned)f2bf(b.y) << 16);
        o.w = f2bf(b.z) | ((unsigned)f2bf(b.w) << 16);
        ((uint4*)xb)[t] = o;
    }

    // degree count (1 edge/thread)
    atomicAdd(&deg[dst[t]], 1);

    // weight pre-pack into MFMA B-fragment order:
    // element (((q*8+c)*64+l)*8 + j) = W[(q&3)*32 + (l>>4)*8 + j][c*16 + (l&15)]
    if (t < 32768) {
        int L   = t >> 14;
        int rem = t & 16383;
        int j2 = rem & 3;
        int l  = (rem >> 2) & 63;
        int c  = (rem >> 8) & 7;
        int q  = rem >> 11;
        const float* W = (L == 0) ? (q < 4 ? Ws1 : Wn1) : (q < 4 ? Ws2 : Wn2);
        int k0  = (q & 3) * 32 + (l >> 4) * 8 + 2 * j2;
        int col = c * 16 + (l & 15);
        float v0 = W[(size_t)k0 * D + col];
        float v1 = W[(size_t)(k0 + 1) * D + col];
        Wp[t] = f2bf(v0) | ((unsigned)f2bf(v1) << 16);
    }
}

// ---------------- segment allocation (order-free CSR) -----------------------

__global__ __launch_bounds__(256) void alloc_rows(
    const int* __restrict__ deg, int* __restrict__ row_start,
    int* __restrict__ cursor, int* __restrict__ alloc_ctr) {
    int i = blockIdx.x * 256 + threadIdx.x;
    int lane = threadIdx.x & 63;
    int pdeg = (i < N_NODES) ? ((deg[i] + 15) & ~15) : 0;
    int incl = pdeg;
    #pragma unroll
    for (int off = 1; off < 64; off <<= 1) {
        int v = __shfl_up(incl, off, 64);
        if (lane >= off) incl += v;
    }
    int waveTotal = __shfl(incl, 63, 64);
    int base = 0;
    if (lane == 63) base = atomicAdd(alloc_ctr, waveTotal);
    base = __shfl(base, 63, 64);
    if (i < N_NODES) {
        int s = base + incl - pdeg;
        row_start[i] = s;
        cursor[i] = s;
    }
}

__global__ void fill_edges(const int* __restrict__ src, const int* __restrict__ dst,
                           int* __restrict__ cursor, int* __restrict__ edge_src) {
    int e = blockIdx.x * 256 + threadIdx.x;
    if (e < N_EDGES) {
        int p = atomicAdd(&cursor[dst[e]], 1);
        edge_src[p] = src[e];
    }
}

// ---------------- fused layer: mean-agg into LDS + dual MFMA GEMM -----------
// block = 32 nodes, 512 threads (8 waves), grid 1250.
// phase A: lane-group g (16 lanes) OWNS node w*4+g: 16 lanes x uint4 = one
//          full 256 B row per gather instruction; 4 nodes progress
//          concurrently per wave. 8 edges/step = 2 broadcast int4 index
//          loads + 8 row gathers per group (32 rows in flight per wave).
//          Lane sub owns feature-dwords sub*4..+3 -> NO cross-lane fold.
// phase B: wave w computes rows (w>>2)*16..+15, cols (w&3)*32..+31;
//          self operand global, neigh operand from LDS mean tile.
// phase C: stage acc to LDS, vectorized bias(+relu) epilogue.

#define PADW 68   // dwords per mean row in LDS (64 data + 4 pad)

__global__ __launch_bounds__(512) void fused_layer(
    const unsigned short* __restrict__ A,     // bf16 plane [N_NODES+1][128]
    const int* __restrict__ row_start,        // padded segment starts
    const int* __restrict__ deg,              // true degrees
    const int* __restrict__ edge_src,         // padded, sentinel = N_NODES
    const unsigned* __restrict__ Wp,          // 16384 uints, fragment order
    const float* __restrict__ bias,
    unsigned short* __restrict__ outb,        // bf16 out (layer 1) or nullptr
    float* __restrict__ outf,                 // f32 out (layer 2) or nullptr
    int do_relu) {
    __shared__ float sf[32 * 132];            // 16896 B; aliased as mean tile
    unsigned* meanL = (unsigned*)sf;          // [32][PADW]

    int tid = threadIdx.x;
    int w = tid >> 6, l = tid & 63;
    int blk = blockIdx.x;
    const uint4* h16 = (const uint4*)A;       // 16 uint4 per 256 B row
    int grp = l >> 4, sub = l & 15;

    // ---- phase A: one node per 16-lane group ----
    {
        int myn = blk * 32 + w * 4 + grp;
        int dgv = deg[myn];
        int e   = row_start[myn];
        int end = e + ((dgv + 15) & ~15);     // multiple of 16 -> 8-steps even
        float a0 = 0.f, a1 = 0.f, a2 = 0.f, a3 = 0.f;
        float a4 = 0.f, a5 = 0.f, a6 = 0.f, a7 = 0.f;
        for (; e < end; e += 8) {
            int4 qa = *(const int4*)&edge_src[e];
            int4 qb = *(const int4*)&edge_src[e + 4];
            uint4 u0 = h16[(size_t)qa.x * 16 + sub];
            uint4 u1 = h16[(size_t)qa.y * 16 + sub];
            uint4 u2 = h16[(size_t)qa.z * 16 + sub];
            uint4 u3 = h16[(size_t)qa.w * 16 + sub];
            uint4 u4 = h16[(size_t)qb.x * 16 + sub];
            uint4 u5 = h16[(size_t)qb.y * 16 + sub];
            uint4 u6 = h16[(size_t)qb.z * 16 + sub];
            uint4 u7 = h16[(size_t)qb.w * 16 + sub];
            a0 += BF_LO(u0.x) + BF_LO(u1.x) + BF_LO(u2.x) + BF_LO(u3.x)
                + BF_LO(u4.x) + BF_LO(u5.x) + BF_LO(u6.x) + BF_LO(u7.x);
            a1 += BF_HI(u0.x) + BF_HI(u1.x) + BF_HI(u2.x) + BF_HI(u3.x)
                + BF_HI(u4.x) + BF_HI(u5.x) + BF_HI(u6.x) + BF_HI(u7.x);
            a2 += BF_LO(u0.y) + BF_LO(u1.y) + BF_LO(u2.y) + BF_LO(u3.y)
                + BF_LO(u4.y) + BF_LO(u5.y) + BF_LO(u6.y) + BF_LO(u7.y);
            a3 += BF_HI(u0.y) + BF_HI(u1.y) + BF_HI(u2.y) + BF_HI(u3.y)
                + BF_HI(u4.y) + BF_HI(u5.y) + BF_HI(u6.y) + BF_HI(u7.y);
            a4 += BF_LO(u0.z) + BF_LO(u1.z) + BF_LO(u2.z) + BF_LO(u3.z)
                + BF_LO(u4.z) + BF_LO(u5.z) + BF_LO(u6.z) + BF_LO(u7.z);
            a5 += BF_HI(u0.z) + BF_HI(u1.z) + BF_HI(u2.z) + BF_HI(u3.z)
                + BF_HI(u4.z) + BF_HI(u5.z) + BF_HI(u6.z) + BF_HI(u7.z);
            a6 += BF_LO(u0.w) + BF_LO(u1.w) + BF_LO(u2.w) + BF_LO(u3.w)
                + BF_LO(u4.w) + BF_LO(u5.w) + BF_LO(u6.w) + BF_LO(u7.w);
            a7 += BF_HI(u0.w) + BF_HI(u1.w) + BF_HI(u2.w) + BF_HI(u3.w)
                + BF_HI(u4.w) + BF_HI(u5.w) + BF_HI(u6.w) + BF_HI(u7.w);
        }
        float inv = dgv > 0 ? 1.0f / (float)dgv : 0.f;
        uint4 o;
        o.x = f2bf(a0 * inv) | ((unsigned)f2bf(a1 * inv) << 16);
        o.y = f2bf(a2 * inv) | ((unsigned)f2bf(a3 * inv) << 16);
        o.z = f2bf(a4 * inv) | ((unsigned)f2bf(a5 * inv) << 16);
        o.w = f2bf(a6 * inv) | ((unsigned)f2bf(a7 * inv) << 16);
        *(uint4*)&meanL[(w * 4 + grp) * PADW + sub * 4] = o;
    }

    // ---- phase B: dual GEMM ----
    int rlo = l & 15, khi = l >> 4;
    int row0g = blk * 32 + (w >> 2) * 16;
    const unsigned short* ar = A + (size_t)(row0g + rlo) * D + khi * 8;

    f32x4 acc[2] = {};
    // self half first: no LDS dependence -> runs before the barrier
    #pragma unroll
    for (int q = 0; q < 4; ++q) {
        short8 a = *(const short8*)(ar + q * 32);
        #pragma unroll
        for (int c = 0; c < 2; ++c) {
            int cg = (w & 3) * 2 + c;
            short8 b = *(const short8*)(Wp + ((q * 8 + cg) * 64 + l) * 4);
            acc[c] = __builtin_amdgcn_mfma_f32_16x16x32_bf16(a, b, acc[c], 0, 0, 0);
        }
    }
    __syncthreads();
    // neigh half from LDS mean tile
    int lr0 = (w >> 2) * 16 + rlo;
    #pragma unroll
    for (int q = 4; q < 8; ++q) {
        short8 a = *(const short8*)(meanL + lr0 * PADW + khi * 4 + (q & 3) * 16);
        #pragma unroll
        for (int c = 0; c < 2; ++c) {
            int cg = (w & 3) * 2 + c;
            short8 b = *(const short8*)(Wp + ((q * 8 + cg) * 64 + l) * 4);
            acc[c] = __builtin_amdgcn_mfma_f32_16x16x32_bf16(a, b, acc[c], 0, 0, 0);
        }
    }
    __syncthreads();   // all reads of meanL done before sf overwrite

    // ---- phase C: epilogue via LDS stage ----
    #pragma unroll
    for (int c = 0; c < 2; ++c) {
        int cg = (w & 3) * 2 + c;
        #pragma unroll
        for (int j = 0; j < 4; ++j)
            sf[((w >> 2) * 16 + khi * 4 + j) * 132 + cg * 16 + rlo] = acc[c][j];
    }
    __syncthreads();

    int row = tid >> 4, c0 = (tid & 15) * 8;
    const float* srow = &sf[row * 132 + c0];
    float4 u0 = *(const float4*)(srow + 0);
    float4 u1 = *(const float4*)(srow + 4);
    float4 b0 = *(const float4*)(bias + c0 + 0);
    float4 b1 = *(const float4*)(bias + c0 + 4);
    size_t grow = (size_t)blk * 32 + row;
    if (do_relu) {
        float f0 = fmaxf(u0.x + b0.x, 0.f), f1 = fmaxf(u0.y + b0.y, 0.f);
        float f2 = fmaxf(u0.z + b0.z, 0.f), f3 = fmaxf(u0.w + b0.w, 0.f);
        float f4 = fmaxf(u1.x + b1.x, 0.f), f5 = fmaxf(u1.y + b1.y, 0.f);
        float f6 = fmaxf(u1.z + b1.z, 0.f), f7 = fmaxf(u1.w + b1.w, 0.f);
        uint4 o;
        o.x = f2bf(f0) | ((unsigned)f2bf(f1) << 16);
        o.y = f2bf(f2) | ((unsigned)f2bf(f3) << 16);
        o.z = f2bf(f4) | ((unsigned)f2bf(f5) << 16);
        o.w = f2bf(f6) | ((unsigned)f2bf(f7) << 16);
        *(uint4*)(outb + grow * D + c0) = o;
    } else {
        float4 o0 = {u0.x + b0.x, u0.y + b0.y, u0.z + b0.z, u0.w + b0.w};
        float4 o1 = {u1.x + b1.x, u1.y + b1.y, u1.z + b1.z, u1.w + b1.w};
        *(float4*)(outf + grow * D + c0 + 0) = o0;
        *(float4*)(outf + grow * D + c0 + 4) = o1;
    }
}

// ---------------- launch ----------------

extern "C" void kernel_launch(void* const* d_in, const int* in_sizes, int n_in,
                              void* d_out, int out_size, void* d_ws, size_t ws_size,
                              hipStream_t stream) {
    const float* x       = (const float*)d_in[0];
    const int*   src     = (const int*)d_in[1];
    const int*   dst     = (const int*)d_in[2];
    const float* W_self1 = (const float*)d_in[3];
    const float* W_neigh1= (const float*)d_in[4];
    const float* b1      = (const float*)d_in[5];
    const float* W_self2 = (const float*)d_in[6];
    const float* W_neigh2= (const float*)d_in[7];
    const float* b2      = (const float*)d_in[8];
    float* out = (float*)d_out;

    char* ws = (char*)d_ws;
    size_t off_deg  = 0;                        // 40000 int
    size_t off_rs   = 160256;                   // 40000 int (256-aligned)
    size_t off_cur  = 320512;                   // 40000 int
    size_t off_es   = 480512;                   // ES_CAP int
    size_t off_xb   = 5600768;                  // (40000+1)*128 bf16
    size_t off_h1b  = 15841024;                 // (40000+1)*128 bf16
    size_t off_wp   = 26081280;                 // 2*16384 uint
    size_t off_ctr  = 26212352;                 // 1 int (alloc counter)
    size_t total    = 26212608;
    if (ws_size < total) return;

    int* deg       = (int*)(ws + off_deg);
    int* row_start = (int*)(ws + off_rs);
    int* cursor    = (int*)(ws + off_cur);
    int* edge_src  = (int*)(ws + off_es);
    unsigned short* xb   = (unsigned short*)(ws + off_xb);
    unsigned short* h1b  = (unsigned short*)(ws + off_h1b);
    unsigned* Wp         = (unsigned*)(ws + off_wp);
    int* alloc_ctr       = (int*)(ws + off_ctr);

    hipMemsetAsync(deg, 0, 160000, stream);
    prep_count<<<2500, 256, 0, stream>>>(x, xb, h1b, W_self1, W_neigh1, W_self2,
                                         W_neigh2, Wp, dst, deg, edge_src, alloc_ctr);
    alloc_rows<<<(N_NODES + 255) / 256, 256, 0, stream>>>(deg, row_start, cursor,
                                                          alloc_ctr);
    fill_edges<<<(N_EDGES + 255) / 256, 256, 0, stream>>>(src, dst, cursor, edge_src);

    fused_layer<<<N_NODES / 32, 512, 0, stream>>>(xb, row_start, deg, edge_src,
                                                  Wp, b1, h1b, nullptr, 1);
    fused_layer<<<N_NODES / 32, 512, 0, stream>>>(h1b, row_start, deg, edge_src,
                                                  Wp + 16384, b2, nullptr, out, 0);
}

// Round 10
// 131.863 us; speedup vs baseline: 1.1006x; 1.1006x over previous
//
#include <hip/hip_runtime.h>

#define N_NODES 40000
#define N_EDGES 640000
#define D 128
#define ES_CAP 1280000   // padded edge capacity: 640000 + 40000*15 = 1.24M max

typedef __attribute__((ext_vector_type(8))) short short8;   // 8 bf16 = 4 VGPR
typedef __attribute__((ext_vector_type(4))) float f32x4;
typedef __attribute__((ext_vector_type(2))) float f32x2;

__device__ __forceinline__ unsigned short f2bf(float f) {
    unsigned u = __float_as_uint(f);
    unsigned r = u + 0x7FFF + ((u >> 16) & 1);   // round-to-nearest-even
    return (unsigned short)(r >> 16);
}

// ---------------- fused prep: x->bf16 + x->fp8, weight pack, degree count, --
// ---------------- edge sentinel fill, zero pad-rows, zero alloc ctr ---------
// grid 2500 x 256 = 640000 threads. deg must be zeroed beforehand (memset).

__global__ __launch_bounds__(256) void prep_count(
    const float* __restrict__ x, unsigned short* __restrict__ xb,
    unsigned short* __restrict__ h1b,
    unsigned char* __restrict__ xq, unsigned char* __restrict__ h1q,
    const float* __restrict__ Ws1, const float* __restrict__ Wn1,
    const float* __restrict__ Ws2, const float* __restrict__ Wn2,
    unsigned* __restrict__ Wp, const int* __restrict__ dst,
    int* __restrict__ deg, int* __restrict__ edge_src,
    int* __restrict__ alloc_ctr) {
    int t = blockIdx.x * 256 + threadIdx.x;

    if (t == 0) *alloc_ctr = 0;

    // sentinel-fill padded edge array (2 slots/thread covers ES_CAP)
    edge_src[t] = N_NODES;
    edge_src[t + 640000] = N_NODES;

    // zero the sentinel rows (row N_NODES) of all planes
    if (t < 64) {
        ((unsigned*)xb)[N_NODES * 64 + t] = 0;
        ((unsigned*)h1b)[N_NODES * 64 + t] = 0;
    }
    if (t < 32) {
        ((unsigned*)xq)[N_NODES * 32 + t] = 0;
        ((unsigned*)h1q)[N_NODES * 32 + t] = 0;
    }

    // fp32 -> bf16 + fp8 feature planes (8 elems/thread)
    {
        float4 a = ((const float4*)x)[t * 2];
        float4 b = ((const float4*)x)[t * 2 + 1];
        uint4 o;
        o.x = f2bf(a.x) | ((unsigned)f2bf(a.y) << 16);
        o.y = f2bf(a.z) | ((unsigned)f2bf(a.w) << 16);
        o.z = f2bf(b.x) | ((unsigned)f2bf(b.y) << 16);
        o.w = f2bf(b.z) | ((unsigned)f2bf(b.w) << 16);
        ((uint4*)xb)[t] = o;
        int p0 = __builtin_amdgcn_cvt_pk_fp8_f32(a.x, a.y, 0, 0);
        p0     = __builtin_amdgcn_cvt_pk_fp8_f32(a.z, a.w, p0, 1);
        int p1 = __builtin_amdgcn_cvt_pk_fp8_f32(b.x, b.y, 0, 0);
        p1     = __builtin_amdgcn_cvt_pk_fp8_f32(b.z, b.w, p1, 1);
        ((uint2*)xq)[t] = make_uint2((unsigned)p0, (unsigned)p1);
    }

    // degree count (1 edge/thread)
    atomicAdd(&deg[dst[t]], 1);

    // weight pre-pack into MFMA B-fragment order (bf16):
    // element (((q*8+c)*64+l)*8 + j) = W[(q&3)*32 + (l>>4)*8 + j][c*16 + (l&15)]
    if (t < 32768) {
        int L   = t >> 14;
        int rem = t & 16383;
        int j2 = rem & 3;
        int l  = (rem >> 2) & 63;
        int c  = (rem >> 8) & 7;
        int q  = rem >> 11;
        const float* W = (L == 0) ? (q < 4 ? Ws1 : Wn1) : (q < 4 ? Ws2 : Wn2);
        int k0  = (q & 3) * 32 + (l >> 4) * 8 + 2 * j2;
        int col = c * 16 + (l & 15);
        float v0 = W[(size_t)k0 * D + col];
        float v1 = W[(size_t)(k0 + 1) * D + col];
        Wp[t] = f2bf(v0) | ((unsigned)f2bf(v1) << 16);
    }
}

// ---------------- segment allocation (order-free CSR) -----------------------

__global__ __launch_bounds__(256) void alloc_rows(
    const int* __restrict__ deg, int* __restrict__ row_start,
    int* __restrict__ cursor, int* __restrict__ alloc_ctr) {
    int i = blockIdx.x * 256 + threadIdx.x;
    int lane = threadIdx.x & 63;
    int pdeg = (i < N_NODES) ? ((deg[i] + 15) & ~15) : 0;
    int incl = pdeg;
    #pragma unroll
    for (int off = 1; off < 64; off <<= 1) {
        int v = __shfl_up(incl, off, 64);
        if (lane >= off) incl += v;
    }
    int waveTotal = __shfl(incl, 63, 64);
    int base = 0;
    if (lane == 63) base = atomicAdd(alloc_ctr, waveTotal);
    base = __shfl(base, 63, 64);
    if (i < N_NODES) {
        int s = base + incl - pdeg;
        row_start[i] = s;
        cursor[i] = s;
    }
}

__global__ void fill_edges(const int* __restrict__ src, const int* __restrict__ dst,
                           int* __restrict__ cursor, int* __restrict__ edge_src) {
    int e = blockIdx.x * 256 + threadIdx.x;
    if (e < N_EDGES) {
        int p = atomicAdd(&cursor[dst[e]], 1);
        if ((unsigned)p < ES_CAP) edge_src[p] = src[e];   // replay-safety clamp
    }
}

// ---------------- fused layer: fp8 mean-agg into LDS + dual bf16 MFMA GEMM --
// block = 32 nodes, 512 threads (8 waves), grid 1250.
// phase A: lane-group g (16 lanes) owns node w*4+g. fp8 rows: 128 B = ONE
//          cache line per edge (halves the L2 line-request count vs bf16).
//          16 lanes x uint2 = one full row per gather instruction; 8 edges
//          per step = 2 broadcast int4 index loads + 8 row gathers (32 lines
//          in flight per wave). Lane sub owns features sub*8..+7; accumulate
//          fp32 via v_cvt_pk_f32_fp8; NO cross-lane fold.
// phase B: wave w computes rows (w>>2)*16..+15, cols (w&3)*32..+31;
//          self operand from bf16 plane, neigh operand from LDS mean tile.
// phase C: stage acc to LDS, vectorized bias(+relu) epilogue; layer 1 also
//          emits the fp8 copy of h1 for layer 2's gather.

#define PADW 68   // dwords per mean row in LDS (64 data + 4 pad)

__global__ __launch_bounds__(512) void fused_layer(
    const unsigned short* __restrict__ A,     // bf16 plane [N_NODES+1][128]
    const unsigned char* __restrict__ Aq,     // fp8 plane  [N_NODES+1][128]
    const int* __restrict__ row_start,        // padded segment starts
    const int* __restrict__ deg,              // true degrees
    const int* __restrict__ edge_src,         // padded, sentinel = N_NODES
    const unsigned* __restrict__ Wp,          // 16384 uints, fragment order
    const float* __restrict__ bias,
    unsigned short* __restrict__ outb,        // bf16 out (layer 1) or nullptr
    unsigned char*  __restrict__ outq,        // fp8 out (layer 1) or nullptr
    float* __restrict__ outf,                 // f32 out (layer 2) or nullptr
    int do_relu) {
    __shared__ float sf[32 * 132];            // 16896 B; aliased as mean tile
    unsigned* meanL = (unsigned*)sf;          // [32][PADW]

    int tid = threadIdx.x;
    int w = tid >> 6, l = tid & 63;
    int blk = blockIdx.x;
    int grp = l >> 4, sub = l & 15;

    // ---- phase A: one node per 16-lane group, fp8 rows ----
    {
        int myn = blk * 32 + w * 4 + grp;
        int dgv = deg[myn];
        int e   = row_start[myn];
        int end = e + ((dgv + 15) & ~15);
        const uint2* q8 = (const uint2*)Aq;   // 16 uint2 per 128 B row
        f32x2 ca = {0.f, 0.f}, cb = {0.f, 0.f}, cc = {0.f, 0.f}, cd = {0.f, 0.f};
        for (; e < end; e += 8) {
            int4 qa = *(const int4*)&edge_src[e];
            int4 qb = *(const int4*)&edge_src[e + 4];
            int i0 = min(qa.x, N_NODES), i1 = min(qa.y, N_NODES);
            int i2 = min(qa.z, N_NODES), i3 = min(qa.w, N_NODES);
            int i4 = min(qb.x, N_NODES), i5 = min(qb.y, N_NODES);
            int i6 = min(qb.z, N_NODES), i7 = min(qb.w, N_NODES);
            uint2 u0 = q8[(size_t)i0 * 16 + sub];
            uint2 u1 = q8[(size_t)i1 * 16 + sub];
            uint2 u2 = q8[(size_t)i2 * 16 + sub];
            uint2 u3 = q8[(size_t)i3 * 16 + sub];
            uint2 u4 = q8[(size_t)i4 * 16 + sub];
            uint2 u5 = q8[(size_t)i5 * 16 + sub];
            uint2 u6 = q8[(size_t)i6 * 16 + sub];
            uint2 u7 = q8[(size_t)i7 * 16 + sub];
            ca += __builtin_amdgcn_cvt_pk_f32_fp8((int)u0.x, 0);
            cb += __builtin_amdgcn_cvt_pk_f32_fp8((int)u0.x, 1);
            cc += __builtin_amdgcn_cvt_pk_f32_fp8((int)u0.y, 0);
            cd += __builtin_amdgcn_cvt_pk_f32_fp8((int)u0.y, 1);
            ca += __builtin_amdgcn_cvt_pk_f32_fp8((int)u1.x, 0);
            cb += __builtin_amdgcn_cvt_pk_f32_fp8((int)u1.x, 1);
            cc += __builtin_amdgcn_cvt_pk_f32_fp8((int)u1.y, 0);
            cd += __builtin_amdgcn_cvt_pk_f32_fp8((int)u1.y, 1);
            ca += __builtin_amdgcn_cvt_pk_f32_fp8((int)u2.x, 0);
            cb += __builtin_amdgcn_cvt_pk_f32_fp8((int)u2.x, 1);
            cc += __builtin_amdgcn_cvt_pk_f32_fp8((int)u2.y, 0);
            cd += __builtin_amdgcn_cvt_pk_f32_fp8((int)u2.y, 1);
            ca += __builtin_amdgcn_cvt_pk_f32_fp8((int)u3.x, 0);
            cb += __builtin_amdgcn_cvt_pk_f32_fp8((int)u3.x, 1);
            cc += __builtin_amdgcn_cvt_pk_f32_fp8((int)u3.y, 0);
            cd += __builtin_amdgcn_cvt_pk_f32_fp8((int)u3.y, 1);
            ca += __builtin_amdgcn_cvt_pk_f32_fp8((int)u4.x, 0);
            cb += __builtin_amdgcn_cvt_pk_f32_fp8((int)u4.x, 1);
            cc += __builtin_amdgcn_cvt_pk_f32_fp8((int)u4.y, 0);
            cd += __builtin_amdgcn_cvt_pk_f32_fp8((int)u4.y, 1);
            ca += __builtin_amdgcn_cvt_pk_f32_fp8((int)u5.x, 0);
            cb += __builtin_amdgcn_cvt_pk_f32_fp8((int)u5.x, 1);
            cc += __builtin_amdgcn_cvt_pk_f32_fp8((int)u5.y, 0);
            cd += __builtin_amdgcn_cvt_pk_f32_fp8((int)u5.y, 1);
            ca += __builtin_amdgcn_cvt_pk_f32_fp8((int)u6.x, 0);
            cb += __builtin_amdgcn_cvt_pk_f32_fp8((int)u6.x, 1);
            cc += __builtin_amdgcn_cvt_pk_f32_fp8((int)u6.y, 0);
            cd += __builtin_amdgcn_cvt_pk_f32_fp8((int)u6.y, 1);
            ca += __builtin_amdgcn_cvt_pk_f32_fp8((int)u7.x, 0);
            cb += __builtin_amdgcn_cvt_pk_f32_fp8((int)u7.x, 1);
            cc += __builtin_amdgcn_cvt_pk_f32_fp8((int)u7.y, 0);
            cd += __builtin_amdgcn_cvt_pk_f32_fp8((int)u7.y, 1);
        }
        float inv = dgv > 0 ? 1.0f / (float)dgv : 0.f;
        uint4 o;
        o.x = f2bf(ca.x * inv) | ((unsigned)f2bf(ca.y * inv) << 16);
        o.y = f2bf(cb.x * inv) | ((unsigned)f2bf(cb.y * inv) << 16);
        o.z = f2bf(cc.x * inv) | ((unsigned)f2bf(cc.y * inv) << 16);
        o.w = f2bf(cd.x * inv) | ((unsigned)f2bf(cd.y * inv) << 16);
        *(uint4*)&meanL[(w * 4 + grp) * PADW + sub * 4] = o;
    }

    // ---- phase B: dual GEMM ----
    int rlo = l & 15, khi = l >> 4;
    int row0g = blk * 32 + (w >> 2) * 16;
    const unsigned short* ar = A + (size_t)(row0g + rlo) * D + khi * 8;

    f32x4 acc[2] = {};
    // self half first: no LDS dependence -> runs before the barrier
    #pragma unroll
    for (int q = 0; q < 4; ++q) {
        short8 a = *(const short8*)(ar + q * 32);
        #pragma unroll
        for (int c = 0; c < 2; ++c) {
            int cg = (w & 3) * 2 + c;
            short8 b = *(const short8*)(Wp + ((q * 8 + cg) * 64 + l) * 4);
            acc[c] = __builtin_amdgcn_mfma_f32_16x16x32_bf16(a, b, acc[c], 0, 0, 0);
        }
    }
    __syncthreads();
    // neigh half from LDS mean tile
    int lr0 = (w >> 2) * 16 + rlo;
    #pragma unroll
    for (int q = 4; q < 8; ++q) {
        short8 a = *(const short8*)(meanL + lr0 * PADW + khi * 4 + (q & 3) * 16);
        #pragma unroll
        for (int c = 0; c < 2; ++c) {
            int cg = (w & 3) * 2 + c;
            short8 b = *(const short8*)(Wp + ((q * 8 + cg) * 64 + l) * 4);
            acc[c] = __builtin_amdgcn_mfma_f32_16x16x32_bf16(a, b, acc[c], 0, 0, 0);
        }
    }
    __syncthreads();   // all reads of meanL done before sf overwrite

    // ---- phase C: epilogue via LDS stage ----
    #pragma unroll
    for (int c = 0; c < 2; ++c) {
        int cg = (w & 3) * 2 + c;
        #pragma unroll
        for (int j = 0; j < 4; ++j)
            sf[((w >> 2) * 16 + khi * 4 + j) * 132 + cg * 16 + rlo] = acc[c][j];
    }
    __syncthreads();

    int row = tid >> 4, c0 = (tid & 15) * 8;
    const float* srow = &sf[row * 132 + c0];
    float4 u0 = *(const float4*)(srow + 0);
    float4 u1 = *(const float4*)(srow + 4);
    float4 b0 = *(const float4*)(bias + c0 + 0);
    float4 b1 = *(const float4*)(bias + c0 + 4);
    size_t grow = (size_t)blk * 32 + row;
    if (do_relu) {
        float f0 = fmaxf(u0.x + b0.x, 0.f), f1 = fmaxf(u0.y + b0.y, 0.f);
        float f2 = fmaxf(u0.z + b0.z, 0.f), f3 = fmaxf(u0.w + b0.w, 0.f);
        float f4 = fmaxf(u1.x + b1.x, 0.f), f5 = fmaxf(u1.y + b1.y, 0.f);
        float f6 = fmaxf(u1.z + b1.z, 0.f), f7 = fmaxf(u1.w + b1.w, 0.f);
        uint4 o;
        o.x = f2bf(f0) | ((unsigned)f2bf(f1) << 16);
        o.y = f2bf(f2) | ((unsigned)f2bf(f3) << 16);
        o.z = f2bf(f4) | ((unsigned)f2bf(f5) << 16);
        o.w = f2bf(f6) | ((unsigned)f2bf(f7) << 16);
        *(uint4*)(outb + grow * D + c0) = o;
        int pq0 = __builtin_amdgcn_cvt_pk_fp8_f32(f0, f1, 0, 0);
        pq0     = __builtin_amdgcn_cvt_pk_fp8_f32(f2, f3, pq0, 1);
        int pq1 = __builtin_amdgcn_cvt_pk_fp8_f32(f4, f5, 0, 0);
        pq1     = __builtin_amdgcn_cvt_pk_fp8_f32(f6, f7, pq1, 1);
        *(uint2*)(outq + grow * D + c0) = make_uint2((unsigned)pq0, (unsigned)pq1);
    } else {
        float4 o0 = {u0.x + b0.x, u0.y + b0.y, u0.z + b0.z, u0.w + b0.w};
        float4 o1 = {u1.x + b1.x, u1.y + b1.y, u1.z + b1.z, u1.w + b1.w};
        *(float4*)(outf + grow * D + c0 + 0) = o0;
        *(float4*)(outf + grow * D + c0 + 4) = o1;
    }
}

// ---------------- launch ----------------

extern "C" void kernel_launch(void* const* d_in, const int* in_sizes, int n_in,
                              void* d_out, int out_size, void* d_ws, size_t ws_size,
                              hipStream_t stream) {
    const float* x       = (const float*)d_in[0];
    const int*   src     = (const int*)d_in[1];
    const int*   dst     = (const int*)d_in[2];
    const float* W_self1 = (const float*)d_in[3];
    const float* W_neigh1= (const float*)d_in[4];
    const float* b1      = (const float*)d_in[5];
    const float* W_self2 = (const float*)d_in[6];
    const float* W_neigh2= (const float*)d_in[7];
    const float* b2      = (const float*)d_in[8];
    float* out = (float*)d_out;

    char* ws = (char*)d_ws;
    size_t off_deg  = 0;                        // 40000 int
    size_t off_rs   = 160256;                   // 40000 int (256-aligned)
    size_t off_cur  = 320512;                   // 40000 int
    size_t off_es   = 480512;                   // ES_CAP int -> 5,600,512
    size_t off_xb   = 5600768;                  // (40001)*128 bf16
    size_t off_h1b  = 15841024;                 // (40001)*128 bf16
    size_t off_wp   = 26081280;                 // 2*16384 uint
    size_t off_ctr  = 26212352;                 // 1 int (alloc counter)
    size_t off_xq   = 26212608;                 // (40001)*128 fp8
    size_t off_h1q  = 31332864;                 // (40001)*128 fp8
    size_t total    = 36453120;
    if (ws_size < total) return;

    int* deg       = (int*)(ws + off_deg);
    int* row_start = (int*)(ws + off_rs);
    int* cursor    = (int*)(ws + off_cur);
    int* edge_src  = (int*)(ws + off_es);
    unsigned short* xb   = (unsigned short*)(ws + off_xb);
    unsigned short* h1b  = (unsigned short*)(ws + off_h1b);
    unsigned* Wp         = (unsigned*)(ws + off_wp);
    int* alloc_ctr       = (int*)(ws + off_ctr);
    unsigned char* xq    = (unsigned char*)(ws + off_xq);
    unsigned char* h1q   = (unsigned char*)(ws + off_h1q);

    hipMemsetAsync(deg, 0, 160000, stream);
    prep_count<<<2500, 256, 0, stream>>>(x, xb, h1b, xq, h1q,
                                         W_self1, W_neigh1, W_self2, W_neigh2,
                                         Wp, dst, deg, edge_src, alloc_ctr);
    alloc_rows<<<(N_NODES + 255) / 256, 256, 0, stream>>>(deg, row_start, cursor,
                                                          alloc_ctr);
    fill_edges<<<(N_EDGES + 255) / 256, 256, 0, stream>>>(src, dst, cursor, edge_src);

    fused_layer<<<N_NODES / 32, 512, 0, stream>>>(xb, xq, row_start, deg, edge_src,
                                                  Wp, b1, h1b, h1q, nullptr, 1);
    fused_layer<<<N_NODES / 32, 512, 0, stream>>>(h1b, h1q, row_start, deg, edge_src,
                                                  Wp + 16384, b2, nullptr, nullptr,
                                                  out, 0);
}

// Round 11
// 96.778 us; speedup vs baseline: 1.4996x; 1.3625x over previous
//
#include <hip/hip_runtime.h>

#define N_NODES 40000
#define N_EDGES 640000
#define D 128
#define CAP 64                      // fixed per-node edge capacity (mean deg 16)
#define ES_CAP (N_NODES * CAP)      // 2,560,000 slots

typedef __attribute__((ext_vector_type(8))) short short8;   // 8 bf16 = 4 VGPR
typedef __attribute__((ext_vector_type(4))) float f32x4;
typedef __attribute__((ext_vector_type(2))) float f32x2;

__device__ __forceinline__ unsigned short f2bf(float f) {
    unsigned u = __float_as_uint(f);
    unsigned r = u + 0x7FFF + ((u >> 16) & 1);   // round-to-nearest-even
    return (unsigned short)(r >> 16);
}

// ---------------- fused prep: cnt zero, x->bf16 + x->fp8, weight pack, ------
// ---------------- edge sentinel fill, zero sentinel rows --------------------
// grid 2500 x 256 = 640000 threads. NO atomics here; counting happens in
// fill_edges (runs after), so zeroing cnt here is race-free.

__global__ __launch_bounds__(256) void prep(
    const float* __restrict__ x, unsigned short* __restrict__ xb,
    unsigned short* __restrict__ h1b,
    unsigned char* __restrict__ xq, unsigned char* __restrict__ h1q,
    const float* __restrict__ Ws1, const float* __restrict__ Wn1,
    const float* __restrict__ Ws2, const float* __restrict__ Wn2,
    unsigned* __restrict__ Wp,
    int* __restrict__ cnt, int* __restrict__ edge_src) {
    int t = blockIdx.x * 256 + threadIdx.x;

    // zero per-node counters
    if (t < N_NODES) cnt[t] = 0;

    // sentinel-fill fixed-capacity edge array (4 slots/thread, int4)
    ((int4*)edge_src)[t] = make_int4(N_NODES, N_NODES, N_NODES, N_NODES);

    // zero the sentinel rows (row N_NODES) of all planes
    if (t < 64) {
        ((unsigned*)xb)[N_NODES * 64 + t] = 0;
        ((unsigned*)h1b)[N_NODES * 64 + t] = 0;
    }
    if (t < 32) {
        ((unsigned*)xq)[N_NODES * 32 + t] = 0;
        ((unsigned*)h1q)[N_NODES * 32 + t] = 0;
    }

    // fp32 -> bf16 + fp8 feature planes (8 elems/thread)
    {
        float4 a = ((const float4*)x)[t * 2];
        float4 b = ((const float4*)x)[t * 2 + 1];
        uint4 o;
        o.x = f2bf(a.x) | ((unsigned)f2bf(a.y) << 16);
        o.y = f2bf(a.z) | ((unsigned)f2bf(a.w) << 16);
        o.z = f2bf(b.x) | ((unsigned)f2bf(b.y) << 16);
        o.w = f2bf(b.z) | ((unsigned)f2bf(b.w) << 16);
        ((uint4*)xb)[t] = o;
        int p0 = __builtin_amdgcn_cvt_pk_fp8_f32(a.x, a.y, 0, 0);
        p0     = __builtin_amdgcn_cvt_pk_fp8_f32(a.z, a.w, p0, 1);
        int p1 = __builtin_amdgcn_cvt_pk_fp8_f32(b.x, b.y, 0, 0);
        p1     = __builtin_amdgcn_cvt_pk_fp8_f32(b.z, b.w, p1, 1);
        ((uint2*)xq)[t] = make_uint2((unsigned)p0, (unsigned)p1);
    }

    // weight pre-pack into MFMA B-fragment order (bf16):
    // element (((q*8+c)*64+l)*8 + j) = W[(q&3)*32 + (l>>4)*8 + j][c*16 + (l&15)]
    if (t < 32768) {
        int L   = t >> 14;
        int rem = t & 16383;
        int j2 = rem & 3;
        int l  = (rem >> 2) & 63;
        int c  = (rem >> 8) & 7;
        int q  = rem >> 11;
        const float* W = (L == 0) ? (q < 4 ? Ws1 : Wn1) : (q < 4 ? Ws2 : Wn2);
        int k0  = (q & 3) * 32 + (l >> 4) * 8 + 2 * j2;
        int col = c * 16 + (l & 15);
        float v0 = W[(size_t)k0 * D + col];
        float v1 = W[(size_t)(k0 + 1) * D + col];
        Wp[t] = f2bf(v0) | ((unsigned)f2bf(v1) << 16);
    }
}

// ---------------- single-pass CSR fill (fixed 64-slot segments) -------------

__global__ void fill_edges(const int* __restrict__ src, const int* __restrict__ dst,
                           int* __restrict__ cnt, int* __restrict__ edge_src) {
    int e = blockIdx.x * 256 + threadIdx.x;
    if (e < N_EDGES) {
        int d = dst[e];
        int p = atomicAdd(&cnt[d], 1);
        if (p < CAP) edge_src[d * CAP + p] = src[e];   // overflow-safe (never hit)
    }
}

// ---------------- fused layer: fp8 mean-agg into LDS + dual bf16 MFMA GEMM --
// block = 32 nodes, 512 threads (8 waves), grid 1250.
// phase A: lane-group g (16 lanes) owns node w*4+g; fp8 rows (128 B = 1 line
//          per edge); 8 edges/step = 2 broadcast int4 index loads + 8 row
//          gathers. Lane sub owns features sub*8..+7; fp32 accumulate via
//          v_cvt_pk_f32_fp8; no cross-lane fold.
// phase B: wave w computes rows (w>>2)*16..+15, cols (w&3)*32..+31;
//          self operand from bf16 plane, neigh operand from LDS mean tile.
// phase C: stage acc to LDS, vectorized bias(+relu) epilogue; layer 1 also
//          emits the fp8 copy of h1 for layer 2's gather.

#define PADW 68   // dwords per mean row in LDS (64 data + 4 pad)

__global__ __launch_bounds__(512) void fused_layer(
    const unsigned short* __restrict__ A,     // bf16 plane [N_NODES+1][128]
    const unsigned char* __restrict__ Aq,     // fp8 plane  [N_NODES+1][128]
    const int* __restrict__ deg,              // true degrees (cnt)
    const int* __restrict__ edge_src,         // fixed-stride, sentinel = N_NODES
    const unsigned* __restrict__ Wp,          // 16384 uints, fragment order
    const float* __restrict__ bias,
    unsigned short* __restrict__ outb,        // bf16 out (layer 1) or nullptr
    unsigned char*  __restrict__ outq,        // fp8 out (layer 1) or nullptr
    float* __restrict__ outf,                 // f32 out (layer 2) or nullptr
    int do_relu) {
    __shared__ float sf[32 * 132];            // 16896 B; aliased as mean tile
    unsigned* meanL = (unsigned*)sf;          // [32][PADW]

    int tid = threadIdx.x;
    int w = tid >> 6, l = tid & 63;
    int blk = blockIdx.x;
    int grp = l >> 4, sub = l & 15;

    // ---- phase A: one node per 16-lane group, fp8 rows ----
    {
        int myn = blk * 32 + w * 4 + grp;
        int dgv = deg[myn];
        int e   = myn * CAP;
        int pd  = (dgv + 15) & ~15;
        if (pd > CAP) pd = CAP;               // replay-safety clamp
        int end = e + pd;
        const uint2* q8 = (const uint2*)Aq;   // 16 uint2 per 128 B row
        f32x2 ca = {0.f, 0.f}, cb = {0.f, 0.f}, cc = {0.f, 0.f}, cd = {0.f, 0.f};
        for (; e < end; e += 8) {
            int4 qa = *(const int4*)&edge_src[e];
            int4 qb = *(const int4*)&edge_src[e + 4];
            uint2 u0 = q8[(size_t)qa.x * 16 + sub];
            uint2 u1 = q8[(size_t)qa.y * 16 + sub];
            uint2 u2 = q8[(size_t)qa.z * 16 + sub];
            uint2 u3 = q8[(size_t)qa.w * 16 + sub];
            uint2 u4 = q8[(size_t)qb.x * 16 + sub];
            uint2 u5 = q8[(size_t)qb.y * 16 + sub];
            uint2 u6 = q8[(size_t)qb.z * 16 + sub];
            uint2 u7 = q8[(size_t)qb.w * 16 + sub];
            ca += __builtin_amdgcn_cvt_pk_f32_fp8((int)u0.x, 0);
            cb += __builtin_amdgcn_cvt_pk_f32_fp8((int)u0.x, 1);
            cc += __builtin_amdgcn_cvt_pk_f32_fp8((int)u0.y, 0);
            cd += __builtin_amdgcn_cvt_pk_f32_fp8((int)u0.y, 1);
            ca += __builtin_amdgcn_cvt_pk_f32_fp8((int)u1.x, 0);
            cb += __builtin_amdgcn_cvt_pk_f32_fp8((int)u1.x, 1);
            cc += __builtin_amdgcn_cvt_pk_f32_fp8((int)u1.y, 0);
            cd += __builtin_amdgcn_cvt_pk_f32_fp8((int)u1.y, 1);
            ca += __builtin_amdgcn_cvt_pk_f32_fp8((int)u2.x, 0);
            cb += __builtin_amdgcn_cvt_pk_f32_fp8((int)u2.x, 1);
            cc += __builtin_amdgcn_cvt_pk_f32_fp8((int)u2.y, 0);
            cd += __builtin_amdgcn_cvt_pk_f32_fp8((int)u2.y, 1);
            ca += __builtin_amdgcn_cvt_pk_f32_fp8((int)u3.x, 0);
            cb += __builtin_amdgcn_cvt_pk_f32_fp8((int)u3.x, 1);
            cc += __builtin_amdgcn_cvt_pk_f32_fp8((int)u3.y, 0);
            cd += __builtin_amdgcn_cvt_pk_f32_fp8((int)u3.y, 1);
            ca += __builtin_amdgcn_cvt_pk_f32_fp8((int)u4.x, 0);
            cb += __builtin_amdgcn_cvt_pk_f32_fp8((int)u4.x, 1);
            cc += __builtin_amdgcn_cvt_pk_f32_fp8((int)u4.y, 0);
            cd += __builtin_amdgcn_cvt_pk_f32_fp8((int)u4.y, 1);
            ca += __builtin_amdgcn_cvt_pk_f32_fp8((int)u5.x, 0);
            cb += __builtin_amdgcn_cvt_pk_f32_fp8((int)u5.x, 1);
            cc += __builtin_amdgcn_cvt_pk_f32_fp8((int)u5.y, 0);
            cd += __builtin_amdgcn_cvt_pk_f32_fp8((int)u5.y, 1);
            ca += __builtin_amdgcn_cvt_pk_f32_fp8((int)u6.x, 0);
            cb += __builtin_amdgcn_cvt_pk_f32_fp8((int)u6.x, 1);
            cc += __builtin_amdgcn_cvt_pk_f32_fp8((int)u6.y, 0);
            cd += __builtin_amdgcn_cvt_pk_f32_fp8((int)u6.y, 1);
            ca += __builtin_amdgcn_cvt_pk_f32_fp8((int)u7.x, 0);
            cb += __builtin_amdgcn_cvt_pk_f32_fp8((int)u7.x, 1);
            cc += __builtin_amdgcn_cvt_pk_f32_fp8((int)u7.y, 0);
            cd += __builtin_amdgcn_cvt_pk_f32_fp8((int)u7.y, 1);
        }
        float inv = dgv > 0 ? 1.0f / (float)dgv : 0.f;
        uint4 o;
        o.x = f2bf(ca.x * inv) | ((unsigned)f2bf(ca.y * inv) << 16);
        o.y = f2bf(cb.x * inv) | ((unsigned)f2bf(cb.y * inv) << 16);
        o.z = f2bf(cc.x * inv) | ((unsigned)f2bf(cc.y * inv) << 16);
        o.w = f2bf(cd.x * inv) | ((unsigned)f2bf(cd.y * inv) << 16);
        *(uint4*)&meanL[(w * 4 + grp) * PADW + sub * 4] = o;
    }

    // ---- phase B: dual GEMM ----
    int rlo = l & 15, khi = l >> 4;
    int row0g = blk * 32 + (w >> 2) * 16;
    const unsigned short* ar = A + (size_t)(row0g + rlo) * D + khi * 8;

    f32x4 acc[2] = {};
    // self half first: no LDS dependence -> runs before the barrier
    #pragma unroll
    for (int q = 0; q < 4; ++q) {
        short8 a = *(const short8*)(ar + q * 32);
        #pragma unroll
        for (int c = 0; c < 2; ++c) {
            int cg = (w & 3) * 2 + c;
            short8 b = *(const short8*)(Wp + ((q * 8 + cg) * 64 + l) * 4);
            acc[c] = __builtin_amdgcn_mfma_f32_16x16x32_bf16(a, b, acc[c], 0, 0, 0);
        }
    }
    __syncthreads();
    // neigh half from LDS mean tile
    int lr0 = (w >> 2) * 16 + rlo;
    #pragma unroll
    for (int q = 4; q < 8; ++q) {
        short8 a = *(const short8*)(meanL + lr0 * PADW + khi * 4 + (q & 3) * 16);
        #pragma unroll
        for (int c = 0; c < 2; ++c) {
            int cg = (w & 3) * 2 + c;
            short8 b = *(const short8*)(Wp + ((q * 8 + cg) * 64 + l) * 4);
            acc[c] = __builtin_amdgcn_mfma_f32_16x16x32_bf16(a, b, acc[c], 0, 0, 0);
        }
    }
    __syncthreads();   // all reads of meanL done before sf overwrite

    // ---- phase C: epilogue via LDS stage ----
    #pragma unroll
    for (int c = 0; c < 2; ++c) {
        int cg = (w & 3) * 2 + c;
        #pragma unroll
        for (int j = 0; j < 4; ++j)
            sf[((w >> 2) * 16 + khi * 4 + j) * 132 + cg * 16 + rlo] = acc[c][j];
    }
    __syncthreads();

    int row = tid >> 4, c0 = (tid & 15) * 8;
    const float* srow = &sf[row * 132 + c0];
    float4 u0 = *(const float4*)(srow + 0);
    float4 u1 = *(const float4*)(srow + 4);
    float4 b0 = *(const float4*)(bias + c0 + 0);
    float4 b1 = *(const float4*)(bias + c0 + 4);
    size_t grow = (size_t)blk * 32 + row;
    if (do_relu) {
        float f0 = fmaxf(u0.x + b0.x, 0.f), f1 = fmaxf(u0.y + b0.y, 0.f);
        float f2 = fmaxf(u0.z + b0.z, 0.f), f3 = fmaxf(u0.w + b0.w, 0.f);
        float f4 = fmaxf(u1.x + b1.x, 0.f), f5 = fmaxf(u1.y + b1.y, 0.f);
        float f6 = fmaxf(u1.z + b1.z, 0.f), f7 = fmaxf(u1.w + b1.w, 0.f);
        uint4 o;
        o.x = f2bf(f0) | ((unsigned)f2bf(f1) << 16);
        o.y = f2bf(f2) | ((unsigned)f2bf(f3) << 16);
        o.z = f2bf(f4) | ((unsigned)f2bf(f5) << 16);
        o.w = f2bf(f6) | ((unsigned)f2bf(f7) << 16);
        *(uint4*)(outb + grow * D + c0) = o;
        int pq0 = __builtin_amdgcn_cvt_pk_fp8_f32(f0, f1, 0, 0);
        pq0     = __builtin_amdgcn_cvt_pk_fp8_f32(f2, f3, pq0, 1);
        int pq1 = __builtin_amdgcn_cvt_pk_fp8_f32(f4, f5, 0, 0);
        pq1     = __builtin_amdgcn_cvt_pk_fp8_f32(f6, f7, pq1, 1);
        *(uint2*)(outq + grow * D + c0) = make_uint2((unsigned)pq0, (unsigned)pq1);
    } else {
        float4 o0 = {u0.x + b0.x, u0.y + b0.y, u0.z + b0.z, u0.w + b0.w};
        float4 o1 = {u1.x + b1.x, u1.y + b1.y, u1.z + b1.z, u1.w + b1.w};
        *(float4*)(outf + grow * D + c0 + 0) = o0;
        *(float4*)(outf + grow * D + c0 + 4) = o1;
    }
}

// ---------------- launch (4 dispatches) ----------------

extern "C" void kernel_launch(void* const* d_in, const int* in_sizes, int n_in,
                              void* d_out, int out_size, void* d_ws, size_t ws_size,
                              hipStream_t stream) {
    const float* x       = (const float*)d_in[0];
    const int*   src     = (const int*)d_in[1];
    const int*   dst     = (const int*)d_in[2];
    const float* W_self1 = (const float*)d_in[3];
    const float* W_neigh1= (const float*)d_in[4];
    const float* b1      = (const float*)d_in[5];
    const float* W_self2 = (const float*)d_in[6];
    const float* W_neigh2= (const float*)d_in[7];
    const float* b2      = (const float*)d_in[8];
    float* out = (float*)d_out;

    char* ws = (char*)d_ws;
    size_t off_cnt  = 0;                        // 40000 int
    size_t off_es   = 160256;                   // ES_CAP int = 10,240,000 B
    size_t off_xb   = 10400512;                 // (40001)*128 bf16 = 10,240,256 B
    size_t off_h1b  = 20640768;                 // (40001)*128 bf16
    size_t off_wp   = 30881024;                 // 2*16384 uint = 131,072 B
    size_t off_xq   = 31012096;                 // (40001)*128 fp8 = 5,120,128 B
    size_t off_h1q  = 36132224;                 // (40001)*128 fp8
    size_t total    = 41252352;
    if (ws_size < total) return;

    int* cnt       = (int*)(ws + off_cnt);
    int* edge_src  = (int*)(ws + off_es);
    unsigned short* xb   = (unsigned short*)(ws + off_xb);
    unsigned short* h1b  = (unsigned short*)(ws + off_h1b);
    unsigned* Wp         = (unsigned*)(ws + off_wp);
    unsigned char* xq    = (unsigned char*)(ws + off_xq);
    unsigned char* h1q   = (unsigned char*)(ws + off_h1q);

    prep<<<2500, 256, 0, stream>>>(x, xb, h1b, xq, h1q,
                                   W_self1, W_neigh1, W_self2, W_neigh2,
                                   Wp, cnt, edge_src);
    fill_edges<<<(N_EDGES + 255) / 256, 256, 0, stream>>>(src, dst, cnt, edge_src);

    fused_layer<<<N_NODES / 32, 512, 0, stream>>>(xb, xq, cnt, edge_src,
                                                  Wp, b1, h1b, h1q, nullptr, 1);
    fused_layer<<<N_NODES / 32, 512, 0, stream>>>(h1b, h1q, cnt, edge_src,
                                                  Wp + 16384, b2, nullptr, nullptr,
                                                  out, 0);
}